// Round 1
// baseline (3189.410 us; speedup 1.0000x reference)
//
#include <hip/hip_runtime.h>
#include <math.h>

#define BB   2
#define SS   2048
#define DD   768
#define HH   12
#define HDIM 64
#define FFD  3072

// ---------------------------------------------------------------------------
// GEMM: C = A(M,K) @ W(N,K)^T + bias, with epilogue variants.
// BM=BN=64, BK=16, 256 threads, 4x4 micro-tile per thread. f32 baseline.
// ---------------------------------------------------------------------------
enum { EP_PLAIN = 0, EP_RELU = 1, EP_SPLIT = 2 };

template <int EPI>
__global__ __launch_bounds__(256) void gemm_nt(
    const float* __restrict__ A, const float* __restrict__ W,
    const float* __restrict__ bias, float* __restrict__ C,
    int M, int N, int K) {
  __shared__ float As[16][64];
  __shared__ float Ws[16][64];
  const int bm = blockIdx.y * 64;
  const int bn = blockIdx.x * 64;
  const int t  = threadIdx.x;
  const int tx = t & 15, ty = t >> 4;

  float acc[4][4] = {};

  for (int k0 = 0; k0 < K; k0 += 16) {
    #pragma unroll
    for (int l = 0; l < 4; ++l) {
      int flat = t + l * 256;        // 0..1023 over 64x16 tile
      int row = flat >> 4, kk = flat & 15;
      As[kk][row] = A[(size_t)(bm + row) * K + k0 + kk];
      Ws[kk][row] = W[(size_t)(bn + row) * K + k0 + kk];
    }
    __syncthreads();
    #pragma unroll
    for (int kk = 0; kk < 16; ++kk) {
      float a[4], w[4];
      #pragma unroll
      for (int i = 0; i < 4; ++i) a[i] = As[kk][ty * 4 + i];
      #pragma unroll
      for (int j = 0; j < 4; ++j) w[j] = Ws[kk][tx * 4 + j];
      #pragma unroll
      for (int i = 0; i < 4; ++i)
        #pragma unroll
        for (int j = 0; j < 4; ++j) acc[i][j] += a[i] * w[j];
    }
    __syncthreads();
  }

  #pragma unroll
  for (int i = 0; i < 4; ++i) {
    int nrow = bm + ty * 4 + i;
    #pragma unroll
    for (int j = 0; j < 4; ++j) {
      int col = bn + tx * 4 + j;
      float val = acc[i][j] + bias[col];
      if (EPI == EP_RELU) val = fmaxf(val, 0.f);
      if (EPI == EP_SPLIT) {
        // write (B,H,S,HD) layout: row n=(b,s), col c=(h,hd)
        int b = nrow >> 11, s = nrow & 2047;
        int h = col >> 6, hd = col & 63;
        C[(((size_t)b * HH + h) * SS + s) * HDIM + hd] = val;
      } else {
        C[(size_t)nrow * N + col] = val;
      }
    }
  }
}

// ---------------------------------------------------------------------------
// Flash-style causal attention with analytic ALiBi.
// grid: (S/64, B*H), block: 64 threads (1 wave). Each thread owns 1 query row.
// q,k,v: (B,H,S,HD) f32. out: (B,S,D) f32.
// ---------------------------------------------------------------------------
__global__ __launch_bounds__(64) void attn_kernel(
    const float* __restrict__ q, const float* __restrict__ k,
    const float* __restrict__ v, float* __restrict__ out) {
  const int qt = blockIdx.x;
  const int bh = blockIdx.y;          // b*H + h
  const int h  = bh % HH;
  const int row = qt * 64 + threadIdx.x;
  const float slope = exp2f(-8.0f * (float)(h + 1) / 12.0f);
  const float scale = 0.125f;         // 1/sqrt(64)

  float qr[64];
  const float* qbase = q + ((size_t)bh * SS + row) * HDIM;
  #pragma unroll
  for (int i = 0; i < 16; ++i) ((float4*)qr)[i] = ((const float4*)qbase)[i];

  float o[64] = {};
  float m = -INFINITY, l = 0.f;

  __shared__ float Ks[64][64];
  __shared__ float Vs[64][64];

  for (int kt = 0; kt <= qt; ++kt) {
    const float* kb = k + ((size_t)bh * SS + kt * 64) * HDIM;
    const float* vb = v + ((size_t)bh * SS + kt * 64) * HDIM;
    __syncthreads();
    #pragma unroll
    for (int i = 0; i < 16; ++i) {
      int f4 = threadIdx.x + i * 64;  // 1024 float4s per tile
      ((float4*)&Ks[0][0])[f4] = ((const float4*)kb)[f4];
      ((float4*)&Vs[0][0])[f4] = ((const float4*)vb)[f4];
    }
    __syncthreads();

    for (int c = 0; c < 4; ++c) {
      float sc[16];
      float cmax = -INFINITY;
      #pragma unroll
      for (int j = 0; j < 16; ++j) {
        int kj = kt * 64 + c * 16 + j;
        float s = 0.f;
        #pragma unroll
        for (int d = 0; d < 64; ++d) s += qr[d] * Ks[c * 16 + j][d];
        s = s * scale + slope * (float)(kj - row);
        if (kj > row) s = -INFINITY;   // causal mask (ref adds -1e9; exp -> 0)
        sc[j] = s;
        cmax = fmaxf(cmax, s);
      }
      if (cmax == -INFINITY) continue; // chunk fully masked
      float mnew = fmaxf(m, cmax);
      float alpha = __expf(m - mnew);  // exp(-inf)=0 on first chunk
      #pragma unroll
      for (int d = 0; d < 64; ++d) o[d] *= alpha;
      l *= alpha;
      #pragma unroll
      for (int j = 0; j < 16; ++j) {
        float p = __expf(sc[j] - mnew);
        l += p;
        #pragma unroll
        for (int d = 0; d < 64; ++d) o[d] += p * Vs[c * 16 + j][d];
      }
      m = mnew;
    }
  }

  // write (B,S,D): out[b][row][h*64+d]
  int b = bh / HH;
  float inv = 1.f / l;
  float* ob = out + ((size_t)b * SS + row) * DD + h * HDIM;
  #pragma unroll
  for (int i = 0; i < 16; ++i) {
    float4 t4;
    t4.x = o[i * 4 + 0] * inv;
    t4.y = o[i * 4 + 1] * inv;
    t4.z = o[i * 4 + 2] * inv;
    t4.w = o[i * 4 + 3] * inv;
    ((float4*)ob)[i] = t4;
  }
}

// ---------------------------------------------------------------------------
// out = LayerNorm(a + r) * g + be   (row-wise over D=768). 1 block per row.
// ---------------------------------------------------------------------------
__global__ __launch_bounds__(256) void resid_ln_kernel(
    const float* __restrict__ a, const float* __restrict__ r,
    const float* __restrict__ g, const float* __restrict__ be,
    float* __restrict__ out) {
  const int row = blockIdx.x;
  const int t = threadIdx.x;
  const size_t base = (size_t)row * DD;

  float v[3];
  float s = 0.f;
  #pragma unroll
  for (int i = 0; i < 3; ++i) {
    int c = t + i * 256;
    v[i] = a[base + c] + r[base + c];
    s += v[i];
  }
  __shared__ float red[256];
  red[t] = s;
  __syncthreads();
  for (int off = 128; off > 0; off >>= 1) {
    if (t < off) red[t] += red[t + off];
    __syncthreads();
  }
  float mu = red[0] * (1.0f / DD);
  __syncthreads();

  float s2 = 0.f;
  #pragma unroll
  for (int i = 0; i < 3; ++i) {
    float d = v[i] - mu;
    s2 += d * d;
  }
  red[t] = s2;
  __syncthreads();
  for (int off = 128; off > 0; off >>= 1) {
    if (t < off) red[t] += red[t + off];
    __syncthreads();
  }
  float var = red[0] * (1.0f / DD);
  float rstd = rsqrtf(var + 1e-5f);

  #pragma unroll
  for (int i = 0; i < 3; ++i) {
    int c = t + i * 256;
    out[base + c] = (v[i] - mu) * rstd * g[c] + be[c];
  }
}

// ---------------------------------------------------------------------------
extern "C" void kernel_launch(void* const* d_in, const int* in_sizes, int n_in,
                              void* d_out, int out_size, void* d_ws, size_t ws_size,
                              hipStream_t stream) {
  const float* x   = (const float*)d_in[0];
  // d_in[1] = mask, d_in[2] = alibi_bias — computed analytically in-kernel.
  const float* wq  = (const float*)d_in[3];
  const float* bq  = (const float*)d_in[4];
  const float* wk  = (const float*)d_in[5];
  const float* bk  = (const float*)d_in[6];
  const float* wv  = (const float*)d_in[7];
  const float* bv  = (const float*)d_in[8];
  const float* wo  = (const float*)d_in[9];
  const float* bo  = (const float*)d_in[10];
  const float* w1  = (const float*)d_in[11];
  const float* b1  = (const float*)d_in[12];
  const float* w2  = (const float*)d_in[13];
  const float* b2  = (const float*)d_in[14];
  const float* g1  = (const float*)d_in[15];
  const float* be1 = (const float*)d_in[16];
  const float* g2  = (const float*)d_in[17];
  const float* be2 = (const float*)d_in[18];
  float* out = (float*)d_out;

  float* ws = (float*)d_ws;
  const size_t SLOT = (size_t)BB * SS * DD;  // 3,145,728 floats (12.6 MB)
  // slot reuse plan (6 slots = 75.5 MB):
  //   slot0: q   -> proj -> ff2
  //   slot1: k   -> x1 (persists to final LN)
  //   slot2-5: v(2), attn_out(3) -> ff1 spans 2..5
  float* qb = ws;
  float* kb = ws + SLOT;
  float* vb = ws + 2 * SLOT;
  float* at = ws + 3 * SLOT;
  float* pj = ws;             // reuse slot0 (q dead after attention)
  float* x1 = ws + SLOT;      // reuse slot1 (k dead)
  float* f1 = ws + 2 * SLOT;  // 4 slots (v, attn dead)
  float* f2 = ws;             // reuse slot0 (proj dead after LN1)

  const int M = BB * SS;  // 4096
  dim3 blk(256);

  // QKV projections, split-heads epilogue
  gemm_nt<EP_SPLIT><<<dim3(DD / 64, M / 64), blk, 0, stream>>>(x, wq, bq, qb, M, DD, DD);
  gemm_nt<EP_SPLIT><<<dim3(DD / 64, M / 64), blk, 0, stream>>>(x, wk, bk, kb, M, DD, DD);
  gemm_nt<EP_SPLIT><<<dim3(DD / 64, M / 64), blk, 0, stream>>>(x, wv, bv, vb, M, DD, DD);

  // Attention (causal + analytic ALiBi), writes (B,S,D)
  attn_kernel<<<dim3(SS / 64, BB * HH), dim3(64), 0, stream>>>(qb, kb, vb, at);

  // Output projection
  gemm_nt<EP_PLAIN><<<dim3(DD / 64, M / 64), blk, 0, stream>>>(at, wo, bo, pj, M, DD, DD);

  // x1 = LN1(x + proj)
  resid_ln_kernel<<<dim3(M), blk, 0, stream>>>(x, pj, g1, be1, x1);

  // FF: relu(x1 @ w1^T + b1) @ w2^T + b2
  gemm_nt<EP_RELU><<<dim3(FFD / 64, M / 64), blk, 0, stream>>>(x1, w1, b1, f1, M, FFD, DD);
  gemm_nt<EP_PLAIN><<<dim3(DD / 64, M / 64), blk, 0, stream>>>(f1, w2, b2, f2, M, DD, FFD);

  // out = LN2(x1 + ff)
  resid_ln_kernel<<<dim3(M), blk, 0, stream>>>(x1, f2, g2, be2, out);
}

// Round 2
// 2707.590 us; speedup vs baseline: 1.1780x; 1.1780x over previous
//
#include <hip/hip_runtime.h>
#include <math.h>

#define BB   2
#define SS   2048
#define DD   768
#define HH   12
#define HDIM 64
#define FFD  3072

typedef __attribute__((ext_vector_type(8))) short bf16x8;   // 8 bf16 in 4 VGPRs
typedef __attribute__((ext_vector_type(4))) float f32x4;

__device__ __forceinline__ unsigned short f2bf(float f) {
  unsigned u = __float_as_uint(f);
  u += 0x7fffu + ((u >> 16) & 1u);
  return (unsigned short)(u >> 16);
}
__device__ __forceinline__ float bf2f(unsigned short s) {
  return __uint_as_float(((unsigned)s) << 16);
}

// ---------------------------------------------------------------------------
// f32 -> bf16 cast, 4 elems/thread (n % 4 == 0)
// ---------------------------------------------------------------------------
__global__ __launch_bounds__(256) void cast_bf16_kernel(
    const float* __restrict__ in, unsigned short* __restrict__ out, int n) {
  int i = (blockIdx.x * 256 + threadIdx.x) * 4;
  if (i < n) {
    float4 f = *(const float4*)&in[i];
    ushort4 o;
    o.x = f2bf(f.x); o.y = f2bf(f.y); o.z = f2bf(f.z); o.w = f2bf(f.w);
    *(ushort4*)&out[i] = o;
  }
}

// ---------------------------------------------------------------------------
// bf16 MFMA GEMM: C = A(M,K) @ W(N,K)^T + bias.
// Block 256 thr = 4 waves, tile 128x128, BK=32. Wave tile 64x64 = 4x4 MFMAs
// of 16x16x32. LDS in quad-major layout [kquad][row][8] so both the MFMA
// A-frag (A[m=lane&15][k=8*quad+j]) and B-frag (W[n=lane&15][k=8*quad+j])
// are single ds_read_b128 per tile. C/D layout: col=lane&15, row=quad*4+reg.
// ---------------------------------------------------------------------------
enum { EP_QKV_F32 = 0, EP_F32 = 1, EP_RELU_BF16 = 2 };

template <int EPI>
__global__ __launch_bounds__(256) void gemm_bt(
    const unsigned short* __restrict__ A, const unsigned short* __restrict__ W,
    const float* __restrict__ bias, void* __restrict__ C,
    int M, int N, int K) {
  __shared__ unsigned short Alds[4 * 128 * 8];
  __shared__ unsigned short Blds[4 * 128 * 8];
  const int bm = blockIdx.y * 128, bn = blockIdx.x * 128;
  const int t = threadIdx.x;
  const int lane = t & 63, wid = t >> 6;
  const int wm = (wid >> 1) * 64, wn = (wid & 1) * 64;
  const int r16 = lane & 15, q4 = lane >> 4;

  f32x4 acc[4][4] = {};

  for (int k0 = 0; k0 < K; k0 += 32) {
    #pragma unroll
    for (int l = 0; l < 2; ++l) {
      int c = t + l * 256;           // 512 chunks of 8 bf16 per matrix
      int row = c >> 2, qd = c & 3;
      *(uint4*)&Alds[(qd * 128 + row) * 8] =
          *(const uint4*)&A[(size_t)(bm + row) * K + k0 + 8 * qd];
      *(uint4*)&Blds[(qd * 128 + row) * 8] =
          *(const uint4*)&W[(size_t)(bn + row) * K + k0 + 8 * qd];
    }
    __syncthreads();
    bf16x8 af[4], bfv[4];
    #pragma unroll
    for (int i = 0; i < 4; ++i)
      af[i] = *(const bf16x8*)&Alds[(q4 * 128 + wm + i * 16 + r16) * 8];
    #pragma unroll
    for (int j = 0; j < 4; ++j)
      bfv[j] = *(const bf16x8*)&Blds[(q4 * 128 + wn + j * 16 + r16) * 8];
    #pragma unroll
    for (int i = 0; i < 4; ++i)
      #pragma unroll
      for (int j = 0; j < 4; ++j)
        acc[i][j] = __builtin_amdgcn_mfma_f32_16x16x32_bf16(af[i], bfv[j], acc[i][j], 0, 0, 0);
    __syncthreads();
  }

  #pragma unroll
  for (int i = 0; i < 4; ++i) {
    #pragma unroll
    for (int j = 0; j < 4; ++j) {
      #pragma unroll
      for (int r = 0; r < 4; ++r) {
        int m = bm + wm + i * 16 + q4 * 4 + r;
        int n = bn + wn + j * 16 + r16;
        float val = acc[i][j][r] + bias[n];
        if (EPI == EP_QKV_F32) {
          // write f32 (B,H,S,HD)
          int b = m >> 11, s = m & 2047;
          int h = n >> 6, hd = n & 63;
          ((float*)C)[(((size_t)b * HH + h) * SS + s) * HDIM + hd] = val;
        } else if (EPI == EP_F32) {
          ((float*)C)[(size_t)m * N + n] = val;
        } else {  // EP_RELU_BF16
          ((unsigned short*)C)[(size_t)m * N + n] = f2bf(fmaxf(val, 0.f));
        }
      }
    }
  }
}

// ---------------------------------------------------------------------------
// Attention v2: flash-style, causal + analytic ALiBi, 4-way split over key
// tiles. Block = 256 thr = 4 waves; all 4 waves own the same 64 query rows,
// wave p handles key tiles kt = p, p+4, ... <= qt with private online-softmax
// state; LDS combine at the end. No __syncthreads in main loop.
// q,k,v: f32 (B,H,S,HD). out: bf16 (B,S,D).
// ---------------------------------------------------------------------------
__global__ __launch_bounds__(256) void attn2_kernel(
    const float* __restrict__ q, const float* __restrict__ k,
    const float* __restrict__ v, unsigned short* __restrict__ out) {
  __shared__ float po[4][64][68];   // +4 pad: breaks the stride-256B bank wall
  __shared__ float pm[4][64];
  __shared__ float pl[4][64];

  const int qt = blockIdx.x;
  const int bh = blockIdx.y;        // b*H + h
  const int h  = bh % HH;
  const int t  = threadIdx.x;
  const int r  = t & 63;            // query row within tile
  const int p  = t >> 6;            // key partition (wave id)
  const int row = qt * 64 + r;
  const float slope = exp2f(-8.0f * (float)(h + 1) / 12.0f);
  const float scale = 0.125f;

  float qr[64];
  const float* qb = q + ((size_t)bh * SS + row) * HDIM;
  #pragma unroll
  for (int i = 0; i < 16; ++i) ((float4*)qr)[i] = ((const float4*)qb)[i];

  float o[64] = {};
  float m = -INFINITY, l = 0.f;

  for (int kt = p; kt <= qt; kt += 4) {
    const float* kb = k + ((size_t)bh * SS + kt * 64) * HDIM;
    const float* vb = v + ((size_t)bh * SS + kt * 64) * HDIM;
    for (int c = 0; c < 4; ++c) {
      float sc[16];
      float cmax = -INFINITY;
      #pragma unroll
      for (int j = 0; j < 16; ++j) {
        int kj = kt * 64 + c * 16 + j;
        const float* kr = kb + (c * 16 + j) * HDIM;
        float s = 0.f;
        #pragma unroll
        for (int d = 0; d < 64; ++d) s += qr[d] * kr[d];
        s = s * scale + slope * (float)(kj - row);
        if (kj > row) s = -INFINITY;
        sc[j] = s;
        cmax = fmaxf(cmax, s);
      }
      if (cmax == -INFINITY) continue;
      float mnew = fmaxf(m, cmax);
      float alpha = __expf(m - mnew);
      #pragma unroll
      for (int d = 0; d < 64; ++d) o[d] *= alpha;
      l *= alpha;
      #pragma unroll
      for (int j = 0; j < 16; ++j) {
        float pe = __expf(sc[j] - mnew);
        l += pe;
        const float* vr = vb + (c * 16 + j) * HDIM;
        #pragma unroll
        for (int d = 0; d < 64; ++d) o[d] += pe * vr[d];
      }
      m = mnew;
    }
  }

  pm[p][r] = m;
  pl[p][r] = l;
  #pragma unroll
  for (int i = 0; i < 16; ++i) ((float4*)&po[p][r][0])[i] = ((const float4*)o)[i];
  __syncthreads();

  if (p == 0) {
    float m4[4], mall = -INFINITY;
    #pragma unroll
    for (int pp = 0; pp < 4; ++pp) {
      m4[pp] = pm[pp][r];
      mall = fmaxf(mall, m4[pp]);
    }
    float w4[4], lall = 0.f;
    #pragma unroll
    for (int pp = 0; pp < 4; ++pp) {
      w4[pp] = (m4[pp] == -INFINITY) ? 0.f : __expf(m4[pp] - mall);
      lall += w4[pp] * pl[pp][r];
    }
    float inv = 1.f / lall;
    int b = bh / HH;
    unsigned short* ob = out + ((size_t)b * SS + row) * DD + h * HDIM;
    #pragma unroll
    for (int d = 0; d < 64; ++d) {
      float s = w4[0] * po[0][r][d] + w4[1] * po[1][r][d] +
                w4[2] * po[2][r][d] + w4[3] * po[3][r][d];
      ob[d] = f2bf(s * inv);
    }
  }
}

// ---------------------------------------------------------------------------
// LN1: x1b(bf16) = LN(x_f32 + pj_f32) * g + be        (1 block / row, D=768)
// LN2: out(f32)  = LN(x1b_bf16 + f2_f32) * g + be
// ---------------------------------------------------------------------------
__global__ __launch_bounds__(256) void ln1_kernel(
    const float* __restrict__ a, const float* __restrict__ rr,
    const float* __restrict__ g, const float* __restrict__ be,
    unsigned short* __restrict__ out) {
  const int row = blockIdx.x, t = threadIdx.x;
  const size_t base = (size_t)row * DD;
  float v[3];
  float s = 0.f;
  #pragma unroll
  for (int i = 0; i < 3; ++i) {
    int c = t + i * 256;
    v[i] = a[base + c] + rr[base + c];
    s += v[i];
  }
  __shared__ float red[256];
  red[t] = s; __syncthreads();
  for (int off = 128; off > 0; off >>= 1) { if (t < off) red[t] += red[t + off]; __syncthreads(); }
  float mu = red[0] * (1.0f / DD);
  __syncthreads();
  float s2 = 0.f;
  #pragma unroll
  for (int i = 0; i < 3; ++i) { float d = v[i] - mu; s2 += d * d; }
  red[t] = s2; __syncthreads();
  for (int off = 128; off > 0; off >>= 1) { if (t < off) red[t] += red[t + off]; __syncthreads(); }
  float rstd = rsqrtf(red[0] * (1.0f / DD) + 1e-5f);
  #pragma unroll
  for (int i = 0; i < 3; ++i) {
    int c = t + i * 256;
    out[base + c] = f2bf((v[i] - mu) * rstd * g[c] + be[c]);
  }
}

__global__ __launch_bounds__(256) void ln2_kernel(
    const unsigned short* __restrict__ a, const float* __restrict__ rr,
    const float* __restrict__ g, const float* __restrict__ be,
    float* __restrict__ out) {
  const int row = blockIdx.x, t = threadIdx.x;
  const size_t base = (size_t)row * DD;
  float v[3];
  float s = 0.f;
  #pragma unroll
  for (int i = 0; i < 3; ++i) {
    int c = t + i * 256;
    v[i] = bf2f(a[base + c]) + rr[base + c];
    s += v[i];
  }
  __shared__ float red[256];
  red[t] = s; __syncthreads();
  for (int off = 128; off > 0; off >>= 1) { if (t < off) red[t] += red[t + off]; __syncthreads(); }
  float mu = red[0] * (1.0f / DD);
  __syncthreads();
  float s2 = 0.f;
  #pragma unroll
  for (int i = 0; i < 3; ++i) { float d = v[i] - mu; s2 += d * d; }
  red[t] = s2; __syncthreads();
  for (int off = 128; off > 0; off >>= 1) { if (t < off) red[t] += red[t + off]; __syncthreads(); }
  float rstd = rsqrtf(red[0] * (1.0f / DD) + 1e-5f);
  #pragma unroll
  for (int i = 0; i < 3; ++i) {
    int c = t + i * 256;
    out[base + c] = (v[i] - mu) * rstd * g[c] + be[c];
  }
}

// ---------------------------------------------------------------------------
extern "C" void kernel_launch(void* const* d_in, const int* in_sizes, int n_in,
                              void* d_out, int out_size, void* d_ws, size_t ws_size,
                              hipStream_t stream) {
  const float* x   = (const float*)d_in[0];
  // d_in[1]=mask, d_in[2]=alibi — analytic in-kernel.
  const float* wq  = (const float*)d_in[3];
  const float* bq  = (const float*)d_in[4];
  const float* wk  = (const float*)d_in[5];
  const float* bk  = (const float*)d_in[6];
  const float* wv  = (const float*)d_in[7];
  const float* bv  = (const float*)d_in[8];
  const float* wo  = (const float*)d_in[9];
  const float* bo  = (const float*)d_in[10];
  const float* w1  = (const float*)d_in[11];
  const float* b1  = (const float*)d_in[12];
  const float* w2  = (const float*)d_in[13];
  const float* b2  = (const float*)d_in[14];
  const float* g1  = (const float*)d_in[15];
  const float* be1 = (const float*)d_in[16];
  const float* g2  = (const float*)d_in[17];
  const float* be2 = (const float*)d_in[18];
  float* out = (float*)d_out;

  char* ws = (char*)d_ws;
  // --- workspace layout (bytes), 64.5 MB total ---
  const size_t W_SM = (size_t)DD * DD * 2;          // 1,179,648 B per 768x768 bf16
  const size_t W_LG = (size_t)FFD * DD * 2;         // 4,718,592 B
  unsigned short* wqb = (unsigned short*)(ws + 0);
  unsigned short* wkb = (unsigned short*)(ws + W_SM);
  unsigned short* wvb = (unsigned short*)(ws + 2 * W_SM);
  unsigned short* wob = (unsigned short*)(ws + 3 * W_SM);
  unsigned short* w1b = (unsigned short*)(ws + 4 * W_SM);
  unsigned short* w2b = (unsigned short*)(ws + 4 * W_SM + W_LG);
  const size_t OFF_XB = 4 * W_SM + 2 * W_LG;        // 14,155,776
  unsigned short* xb = (unsigned short*)(ws + OFF_XB);          // 6,291,456 B
  const size_t OFF_R1 = OFF_XB + 6291456;           // REG1: 25,165,824 B
  const size_t OFF_R2 = OFF_R1 + 25165824;          // REG2: 18,874,368 B
  float* qf = (float*)(ws + OFF_R1);                             // 12.58 MB
  float* kf = (float*)(ws + OFF_R1 + 12582912);                  // 12.58 MB
  float* vf = (float*)(ws + OFF_R2);                             // 12.58 MB
  unsigned short* at = (unsigned short*)(ws + OFF_R2 + 12582912);// 6.29 MB
  float* pj  = (float*)(ws + OFF_R1);               // reuse qf (dead after attn)
  unsigned short* x1b = (unsigned short*)(ws + OFF_R2);          // reuse vf
  unsigned short* f1  = (unsigned short*)(ws + OFF_R1);          // reuse pj+kf (25.17 MB)
  float* f2 = (float*)(ws + OFF_R2 + 6291456);      // reuse rest of REG2 (12.58 MB)

  const int M = BB * SS;  // 4096
  dim3 blk(256);

  // casts to bf16
  cast_bf16_kernel<<<dim3((M * DD / 4 + 255) / 256), blk, 0, stream>>>(x, xb, M * DD);
  cast_bf16_kernel<<<dim3((DD * DD / 4 + 255) / 256), blk, 0, stream>>>(wq, wqb, DD * DD);
  cast_bf16_kernel<<<dim3((DD * DD / 4 + 255) / 256), blk, 0, stream>>>(wk, wkb, DD * DD);
  cast_bf16_kernel<<<dim3((DD * DD / 4 + 255) / 256), blk, 0, stream>>>(wv, wvb, DD * DD);
  cast_bf16_kernel<<<dim3((DD * DD / 4 + 255) / 256), blk, 0, stream>>>(wo, wob, DD * DD);
  cast_bf16_kernel<<<dim3((FFD * DD / 4 + 255) / 256), blk, 0, stream>>>(w1, w1b, FFD * DD);
  cast_bf16_kernel<<<dim3((FFD * DD / 4 + 255) / 256), blk, 0, stream>>>(w2, w2b, FFD * DD);

  // QKV projections -> f32 (B,H,S,HD)
  gemm_bt<EP_QKV_F32><<<dim3(DD / 128, M / 128), blk, 0, stream>>>(xb, wqb, bq, qf, M, DD, DD);
  gemm_bt<EP_QKV_F32><<<dim3(DD / 128, M / 128), blk, 0, stream>>>(xb, wkb, bk, kf, M, DD, DD);
  gemm_bt<EP_QKV_F32><<<dim3(DD / 128, M / 128), blk, 0, stream>>>(xb, wvb, bv, vf, M, DD, DD);

  // attention -> at (bf16, (B,S,D))
  attn2_kernel<<<dim3(SS / 64, BB * HH), blk, 0, stream>>>(qf, kf, vf, at);

  // output projection -> pj (f32)
  gemm_bt<EP_F32><<<dim3(DD / 128, M / 128), blk, 0, stream>>>(at, wob, bo, pj, M, DD, DD);

  // x1b = bf16(LN(x + pj))
  ln1_kernel<<<dim3(M), blk, 0, stream>>>(x, pj, g1, be1, x1b);

  // FF1: relu(x1 @ w1^T + b1) -> f1 (bf16)
  gemm_bt<EP_RELU_BF16><<<dim3(FFD / 128, M / 128), blk, 0, stream>>>(x1b, w1b, b1, f1, M, FFD, DD);

  // FF2 -> f2 (f32)
  gemm_bt<EP_F32><<<dim3(DD / 128, M / 128), blk, 0, stream>>>(f1, w2b, b2, f2, M, DD, FFD);

  // out = LN(x1 + f2)
  ln2_kernel<<<dim3(M), blk, 0, stream>>>(x1b, f2, g2, be2, out);
}

// Round 3
// 626.210 us; speedup vs baseline: 5.0932x; 4.3238x over previous
//
#include <hip/hip_runtime.h>
#include <math.h>

#define BB   2
#define SS   2048
#define DD   768
#define HH   12
#define HDIM 64
#define FFD  3072

typedef __attribute__((ext_vector_type(8))) short bf16x8;   // 8 bf16 in 4 VGPRs
typedef __attribute__((ext_vector_type(4))) float f32x4;

__device__ __forceinline__ unsigned short f2bf(float f) {
  unsigned u = __float_as_uint(f);
  u += 0x7fffu + ((u >> 16) & 1u);
  return (unsigned short)(u >> 16);
}
__device__ __forceinline__ float bf2f(unsigned short s) {
  return __uint_as_float(((unsigned)s) << 16);
}

// ---------------------------------------------------------------------------
// f32 -> bf16 cast, 4 elems/thread (n % 4 == 0)
// ---------------------------------------------------------------------------
__global__ __launch_bounds__(256) void cast_bf16_kernel(
    const float* __restrict__ in, unsigned short* __restrict__ out, int n) {
  int i = (blockIdx.x * 256 + threadIdx.x) * 4;
  if (i < n) {
    float4 f = *(const float4*)&in[i];
    ushort4 o;
    o.x = f2bf(f.x); o.y = f2bf(f.y); o.z = f2bf(f.z); o.w = f2bf(f.w);
    *(ushort4*)&out[i] = o;
  }
}

// ---------------------------------------------------------------------------
// bf16 MFMA GEMM: C = A(M,K) @ W(N,K)^T + bias. 128x128 tile, BK=32,
// 4 waves x (64x64), quad-major LDS layout, ds_read_b128 frags.
// EP_QKV3_BF16: fused QKV epilogue -> 3 bf16 (B,H,S,HD) tensors.
// ---------------------------------------------------------------------------
enum { EP_F32 = 0, EP_RELU_BF16 = 1, EP_QKV3_BF16 = 2 };

template <int EPI>
__global__ __launch_bounds__(256) void gemm_bt(
    const unsigned short* __restrict__ A, const unsigned short* __restrict__ W,
    const float* __restrict__ bias, void* __restrict__ C0,
    void* __restrict__ C1, void* __restrict__ C2,
    int M, int N, int K) {
  __shared__ unsigned short Alds[4 * 128 * 8];
  __shared__ unsigned short Blds[4 * 128 * 8];
  const int bm = blockIdx.y * 128, bn = blockIdx.x * 128;
  const int t = threadIdx.x;
  const int lane = t & 63, wid = t >> 6;
  const int wm = (wid >> 1) * 64, wn = (wid & 1) * 64;
  const int r16 = lane & 15, q4 = lane >> 4;

  f32x4 acc[4][4] = {};

  for (int k0 = 0; k0 < K; k0 += 32) {
    #pragma unroll
    for (int l = 0; l < 2; ++l) {
      int c = t + l * 256;           // 512 chunks of 8 bf16 per matrix
      int row = c >> 2, qd = c & 3;
      *(uint4*)&Alds[(qd * 128 + row) * 8] =
          *(const uint4*)&A[(size_t)(bm + row) * K + k0 + 8 * qd];
      *(uint4*)&Blds[(qd * 128 + row) * 8] =
          *(const uint4*)&W[(size_t)(bn + row) * K + k0 + 8 * qd];
    }
    __syncthreads();
    bf16x8 af[4], bfv[4];
    #pragma unroll
    for (int i = 0; i < 4; ++i)
      af[i] = *(const bf16x8*)&Alds[(q4 * 128 + wm + i * 16 + r16) * 8];
    #pragma unroll
    for (int j = 0; j < 4; ++j)
      bfv[j] = *(const bf16x8*)&Blds[(q4 * 128 + wn + j * 16 + r16) * 8];
    #pragma unroll
    for (int i = 0; i < 4; ++i)
      #pragma unroll
      for (int j = 0; j < 4; ++j)
        acc[i][j] = __builtin_amdgcn_mfma_f32_16x16x32_bf16(af[i], bfv[j], acc[i][j], 0, 0, 0);
    __syncthreads();
  }

  #pragma unroll
  for (int i = 0; i < 4; ++i) {
    #pragma unroll
    for (int j = 0; j < 4; ++j) {
      #pragma unroll
      for (int r = 0; r < 4; ++r) {
        int m = bm + wm + i * 16 + q4 * 4 + r;
        int n = bn + wn + j * 16 + r16;
        float val = acc[i][j][r] + bias[n];
        if (EPI == EP_QKV3_BF16) {
          int mat = (n >= 1536) ? 2 : (n >= 768 ? 1 : 0);
          int c = n - mat * 768;
          int b = m >> 11, s = m & 2047;
          int h = c >> 6, hd = c & 63;
          unsigned short* dst = (unsigned short*)(mat == 0 ? C0 : (mat == 1 ? C1 : C2));
          dst[(((size_t)b * HH + h) * SS + s) * HDIM + hd] = f2bf(val);
        } else if (EPI == EP_F32) {
          ((float*)C0)[(size_t)m * N + n] = val;
        } else {  // EP_RELU_BF16
          ((unsigned short*)C0)[(size_t)m * N + n] = f2bf(fmaxf(val, 0.f));
        }
      }
    }
  }
}

// ---------------------------------------------------------------------------
// Attention v3: MFMA flash attention, causal + analytic ALiBi.
// Block = 4 waves; each wave owns 32 query rows of a 128-row Q tile for one
// (b,h). K tile (64x64) and V^T tile staged in padded LDS (stride 80 u16),
// shared by all waves. QK^T and PV via mfma_f32_16x16x32_bf16; softmax in
// f32 on C-layout regs with quad-local shfl_xor reductions; P transits LDS
// (C-layout -> A-layout). qt reversed for causal load balance.
// Q,K,V bf16 (B,H,S,HD); out bf16 (B,S,D).
// ---------------------------------------------------------------------------
#define KSTR 80   // padded LDS row stride (u16): 160B -> 4-way worst conflicts

__global__ __launch_bounds__(256) void attn3_kernel(
    const unsigned short* __restrict__ Q, const unsigned short* __restrict__ K,
    const unsigned short* __restrict__ V, unsigned short* __restrict__ out) {
  __shared__ unsigned short Klds[64 * KSTR];       // [key][dim]
  __shared__ unsigned short Vt[64 * KSTR];         // [dim][key]
  __shared__ unsigned short Plds[4 * 32 * KSTR];   // per-wave [q][key]

  const int qt = (SS / 128 - 1) - blockIdx.x;      // reversed: long blocks first
  const int bh = blockIdx.y;
  const int h = bh % HH;
  const int b = bh / HH;
  const int t = threadIdx.x;
  const int lane = t & 63, w = t >> 6;
  const int r16 = lane & 15, q4 = lane >> 4;
  const float slope = exp2f(-8.0f * (float)(h + 1) / 12.0f);
  const float scale = 0.125f;

  // Q frags (held in regs for the whole kernel): A[m=r16][k=q4*8+j]
  bf16x8 qf[2][2];
  {
    const unsigned short* qbase = Q + ((size_t)bh * SS + qt * 128 + w * 32) * HDIM;
    #pragma unroll
    for (int i = 0; i < 2; ++i)
      #pragma unroll
      for (int ks = 0; ks < 2; ++ks)
        qf[i][ks] = *(const bf16x8*)(qbase + (i * 16 + r16) * HDIM + ks * 32 + q4 * 8);
  }

  f32x4 O[2][4] = {};
  float mrow[2][4], lrow[2][4];
  #pragma unroll
  for (int i = 0; i < 2; ++i)
    #pragma unroll
    for (int r = 0; r < 4; ++r) { mrow[i][r] = -INFINITY; lrow[i][r] = 0.f; }

  const int ktmax = 2 * qt + 1;
  const int wave_max_row = qt * 128 + w * 32 + 31;
  unsigned short* Pw = &Plds[w * 32 * KSTR];

  for (int kt = 0; kt <= ktmax; ++kt) {
    __syncthreads();   // prior tile's frag reads done before restaging
    {
      // K: 512 ushort8 chunks, direct copy into [key][dim] (stride KSTR)
      const unsigned short* kg = K + ((size_t)bh * SS + kt * 64) * HDIM;
      #pragma unroll
      for (int l = 0; l < 2; ++l) {
        int cc = t + l * 256;
        int key = cc >> 3, dq = cc & 7;
        *(uint4*)&Klds[key * KSTR + dq * 8] = *(const uint4*)(kg + key * HDIM + dq * 8);
      }
      // V transposed: key-pairs packed as u32 -> conflict-free b32 writes
      const unsigned short* vg = V + ((size_t)bh * SS + kt * 64) * HDIM;
      int kp = t & 31, dq = t >> 5;
      bf16x8 v0 = *(const bf16x8*)(vg + (2 * kp) * HDIM + dq * 8);
      bf16x8 v1 = *(const bf16x8*)(vg + (2 * kp + 1) * HDIM + dq * 8);
      #pragma unroll
      for (int e = 0; e < 8; ++e) {
        unsigned u = ((unsigned)(unsigned short)v0[e]) |
                     (((unsigned)(unsigned short)v1[e]) << 16);
        *(unsigned*)&Vt[(dq * 8 + e) * KSTR + 2 * kp] = u;
      }
    }
    __syncthreads();
    if (kt * 64 > wave_max_row) continue;   // tile fully masked for this wave

    // ---- QK^T ----
    f32x4 sc[2][4] = {};
    #pragma unroll
    for (int ks = 0; ks < 2; ++ks) {
      bf16x8 kf[4];
      #pragma unroll
      for (int jb = 0; jb < 4; ++jb)
        kf[jb] = *(const bf16x8*)&Klds[(jb * 16 + r16) * KSTR + ks * 32 + q4 * 8];
      #pragma unroll
      for (int i = 0; i < 2; ++i)
        #pragma unroll
        for (int jb = 0; jb < 4; ++jb)
          sc[i][jb] = __builtin_amdgcn_mfma_f32_16x16x32_bf16(qf[i][ks], kf[jb], sc[i][jb], 0, 0, 0);
    }

    // ---- online softmax (C layout: row = i*16+q4*4+r, col = jb*16+r16) ----
    const int q0 = qt * 128 + w * 32 + q4 * 4;
    #pragma unroll
    for (int i = 0; i < 2; ++i) {
      #pragma unroll
      for (int r = 0; r < 4; ++r) {
        int qrow = q0 + i * 16 + r;
        int d0 = kt * 64 + r16 - qrow;
        float tmp[4];
        float mx = -INFINITY;
        #pragma unroll
        for (int jb = 0; jb < 4; ++jb) {
          int diff = d0 + jb * 16;
          float vv = sc[i][jb][r] * scale + slope * (float)diff;
          vv = (diff <= 0) ? vv : -INFINITY;
          tmp[jb] = vv;
          mx = fmaxf(mx, vv);
        }
        #pragma unroll
        for (int off = 1; off < 16; off <<= 1) mx = fmaxf(mx, __shfl_xor(mx, off, 64));
        float mold = mrow[i][r];
        float mn = fmaxf(mold, mx);
        float alpha = __expf(mold - mn);   // exp(-inf)=0 on first live tile
        mrow[i][r] = mn;
        float rs = 0.f;
        #pragma unroll
        for (int jb = 0; jb < 4; ++jb) {
          float p = __expf(tmp[jb] - mn);
          rs += p;
          Pw[(i * 16 + q4 * 4 + r) * KSTR + jb * 16 + r16] = f2bf(p);
        }
        #pragma unroll
        for (int off = 1; off < 16; off <<= 1) rs += __shfl_xor(rs, off, 64);
        lrow[i][r] = lrow[i][r] * alpha + rs;
        #pragma unroll
        for (int jb2 = 0; jb2 < 4; ++jb2) O[i][jb2][r] *= alpha;
      }
    }

    // ---- PV (P from LDS in A layout; Vt gives B[n=dim][k=key]) ----
    #pragma unroll
    for (int ks = 0; ks < 2; ++ks) {
      bf16x8 pf[2], vf[4];
      #pragma unroll
      for (int i = 0; i < 2; ++i)
        pf[i] = *(const bf16x8*)&Pw[(i * 16 + r16) * KSTR + ks * 32 + q4 * 8];
      #pragma unroll
      for (int jb2 = 0; jb2 < 4; ++jb2)
        vf[jb2] = *(const bf16x8*)&Vt[(jb2 * 16 + r16) * KSTR + ks * 32 + q4 * 8];
      #pragma unroll
      for (int i = 0; i < 2; ++i)
        #pragma unroll
        for (int jb2 = 0; jb2 < 4; ++jb2)
          O[i][jb2] = __builtin_amdgcn_mfma_f32_16x16x32_bf16(pf[i], vf[jb2], O[i][jb2], 0, 0, 0);
    }
  }

  // ---- epilogue: normalize, write bf16 (B,S,D) ----
  #pragma unroll
  for (int i = 0; i < 2; ++i) {
    #pragma unroll
    for (int r = 0; r < 4; ++r) {
      float inv = 1.f / lrow[i][r];
      int qg = qt * 128 + w * 32 + i * 16 + q4 * 4 + r;
      unsigned short* ob = out + ((size_t)b * SS + qg) * DD + h * HDIM;
      #pragma unroll
      for (int jb2 = 0; jb2 < 4; ++jb2)
        ob[jb2 * 16 + r16] = f2bf(O[i][jb2][r] * inv);
    }
  }
}

// ---------------------------------------------------------------------------
// LN kernels (1 block / row, D=768)
// ---------------------------------------------------------------------------
__global__ __launch_bounds__(256) void ln1_kernel(
    const float* __restrict__ a, const float* __restrict__ rr,
    const float* __restrict__ g, const float* __restrict__ be,
    unsigned short* __restrict__ out) {
  const int row = blockIdx.x, t = threadIdx.x;
  const size_t base = (size_t)row * DD;
  float v[3];
  float s = 0.f;
  #pragma unroll
  for (int i = 0; i < 3; ++i) {
    int c = t + i * 256;
    v[i] = a[base + c] + rr[base + c];
    s += v[i];
  }
  __shared__ float red[256];
  red[t] = s; __syncthreads();
  for (int off = 128; off > 0; off >>= 1) { if (t < off) red[t] += red[t + off]; __syncthreads(); }
  float mu = red[0] * (1.0f / DD);
  __syncthreads();
  float s2 = 0.f;
  #pragma unroll
  for (int i = 0; i < 3; ++i) { float d = v[i] - mu; s2 += d * d; }
  red[t] = s2; __syncthreads();
  for (int off = 128; off > 0; off >>= 1) { if (t < off) red[t] += red[t + off]; __syncthreads(); }
  float rstd = rsqrtf(red[0] * (1.0f / DD) + 1e-5f);
  #pragma unroll
  for (int i = 0; i < 3; ++i) {
    int c = t + i * 256;
    out[base + c] = f2bf((v[i] - mu) * rstd * g[c] + be[c]);
  }
}

__global__ __launch_bounds__(256) void ln2_kernel(
    const unsigned short* __restrict__ a, const float* __restrict__ rr,
    const float* __restrict__ g, const float* __restrict__ be,
    float* __restrict__ out) {
  const int row = blockIdx.x, t = threadIdx.x;
  const size_t base = (size_t)row * DD;
  float v[3];
  float s = 0.f;
  #pragma unroll
  for (int i = 0; i < 3; ++i) {
    int c = t + i * 256;
    v[i] = bf2f(a[base + c]) + rr[base + c];
    s += v[i];
  }
  __shared__ float red[256];
  red[t] = s; __syncthreads();
  for (int off = 128; off > 0; off >>= 1) { if (t < off) red[t] += red[t + off]; __syncthreads(); }
  float mu = red[0] * (1.0f / DD);
  __syncthreads();
  float s2 = 0.f;
  #pragma unroll
  for (int i = 0; i < 3; ++i) { float d = v[i] - mu; s2 += d * d; }
  red[t] = s2; __syncthreads();
  for (int off = 128; off > 0; off >>= 1) { if (t < off) red[t] += red[t + off]; __syncthreads(); }
  float rstd = rsqrtf(red[0] * (1.0f / DD) + 1e-5f);
  #pragma unroll
  for (int i = 0; i < 3; ++i) {
    int c = t + i * 256;
    out[base + c] = (v[i] - mu) * rstd * g[c] + be[c];
  }
}

// ---------------------------------------------------------------------------
extern "C" void kernel_launch(void* const* d_in, const int* in_sizes, int n_in,
                              void* d_out, int out_size, void* d_ws, size_t ws_size,
                              hipStream_t stream) {
  const float* x   = (const float*)d_in[0];
  // d_in[1]=mask, d_in[2]=alibi — analytic in-kernel.
  const float* wq  = (const float*)d_in[3];
  const float* bq  = (const float*)d_in[4];
  const float* wk  = (const float*)d_in[5];
  const float* bk  = (const float*)d_in[6];
  const float* wv  = (const float*)d_in[7];
  const float* bv  = (const float*)d_in[8];
  const float* wo  = (const float*)d_in[9];
  const float* bo  = (const float*)d_in[10];
  const float* w1  = (const float*)d_in[11];
  const float* b1  = (const float*)d_in[12];
  const float* w2  = (const float*)d_in[13];
  const float* b2  = (const float*)d_in[14];
  const float* g1  = (const float*)d_in[15];
  const float* be1 = (const float*)d_in[16];
  const float* g2  = (const float*)d_in[17];
  const float* be2 = (const float*)d_in[18];
  float* out = (float*)d_out;

  char* ws = (char*)d_ws;
  // --- workspace layout (bytes), total 70.8 MB ---
  unsigned short* wqkvb = (unsigned short*)(ws + 0);          //  3,538,944 (2304x768)
  unsigned short* wob   = (unsigned short*)(ws + 3538944);    //  1,179,648
  unsigned short* w1b   = (unsigned short*)(ws + 4718592);    //  4,718,592
  unsigned short* w2b   = (unsigned short*)(ws + 9437184);    //  4,718,592
  unsigned short* xb    = (unsigned short*)(ws + 14155776);   //  6,291,456
  float*          bqkv  = (float*)(ws + 20447232);            //      9,216
  unsigned short* qb    = (unsigned short*)(ws + 20456448);   //  6,291,456
  unsigned short* kb    = (unsigned short*)(ws + 26747904);   //  6,291,456
  unsigned short* vb    = (unsigned short*)(ws + 33039360);   //  6,291,456
  unsigned short* at    = (unsigned short*)(ws + 39330816);   //  6,291,456
  unsigned short* f1    = (unsigned short*)(ws + 45622272);   // 25,165,824
  // reuse (liveness-checked):
  float*          pj    = (float*)(ws + 20456448);            // over qb+kb (dead post-attn)
  unsigned short* x1b   = (unsigned short*)(ws + 33039360);   // over vb   (dead post-attn)
  float*          f2    = (float*)(ws + 20456448);            // over pj   (dead post-ln1)

  const int M = BB * SS;  // 4096
  dim3 blk(256);

  // bf16 casts; wq/wk/wv concatenated row-wise into one (2304,768) matrix
  cast_bf16_kernel<<<dim3(M * DD / 1024), blk, 0, stream>>>(x, xb, M * DD);
  cast_bf16_kernel<<<dim3(DD * DD / 1024), blk, 0, stream>>>(wq, wqkvb, DD * DD);
  cast_bf16_kernel<<<dim3(DD * DD / 1024), blk, 0, stream>>>(wk, wqkvb + DD * DD, DD * DD);
  cast_bf16_kernel<<<dim3(DD * DD / 1024), blk, 0, stream>>>(wv, wqkvb + 2 * DD * DD, DD * DD);
  cast_bf16_kernel<<<dim3(DD * DD / 1024), blk, 0, stream>>>(wo, wob, DD * DD);
  cast_bf16_kernel<<<dim3(FFD * DD / 1024), blk, 0, stream>>>(w1, w1b, FFD * DD);
  cast_bf16_kernel<<<dim3(FFD * DD / 1024), blk, 0, stream>>>(w2, w2b, FFD * DD);
  hipMemcpyAsync(bqkv, bq, DD * sizeof(float), hipMemcpyDeviceToDevice, stream);
  hipMemcpyAsync(bqkv + DD, bk, DD * sizeof(float), hipMemcpyDeviceToDevice, stream);
  hipMemcpyAsync(bqkv + 2 * DD, bv, DD * sizeof(float), hipMemcpyDeviceToDevice, stream);

  // fused QKV projection: (4096 x 2304) = xb @ [wq;wk;wv]^T -> bf16 (B,H,S,HD)
  gemm_bt<EP_QKV3_BF16><<<dim3(3 * DD / 128, M / 128), blk, 0, stream>>>(
      xb, wqkvb, bqkv, qb, kb, vb, M, 3 * DD, DD);

  // MFMA flash attention -> at (bf16, (B,S,D))
  attn3_kernel<<<dim3(SS / 128, BB * HH), blk, 0, stream>>>(qb, kb, vb, at);

  // output projection -> pj (f32)
  gemm_bt<EP_F32><<<dim3(DD / 128, M / 128), blk, 0, stream>>>(
      at, wob, bo, pj, nullptr, nullptr, M, DD, DD);

  // x1b = bf16(LN(x + pj))
  ln1_kernel<<<dim3(M), blk, 0, stream>>>(x, pj, g1, be1, x1b);

  // FF1: relu(x1 @ w1^T + b1) -> f1 (bf16)
  gemm_bt<EP_RELU_BF16><<<dim3(FFD / 128, M / 128), blk, 0, stream>>>(
      x1b, w1b, b1, f1, nullptr, nullptr, M, FFD, DD);

  // FF2 -> f2 (f32)
  gemm_bt<EP_F32><<<dim3(DD / 128, M / 128), blk, 0, stream>>>(
      f1, w2b, b2, f2, nullptr, nullptr, M, DD, FFD);

  // out = LN(x1 + f2)
  ln2_kernel<<<dim3(M), blk, 0, stream>>>(x1b, f2, g2, be2, out);
}

// Round 4
// 567.934 us; speedup vs baseline: 5.6158x; 1.1026x over previous
//
#include <hip/hip_runtime.h>
#include <math.h>

#define BB   2
#define SS   2048
#define DD   768
#define HH   12
#define HDIM 64
#define FFD  3072

typedef __attribute__((ext_vector_type(8))) short bf16x8;   // 8 bf16 in 4 VGPRs
typedef __attribute__((ext_vector_type(4))) float f32x4;

__device__ __forceinline__ unsigned short f2bf(float f) {
  unsigned u = __float_as_uint(f);
  u += 0x7fffu + ((u >> 16) & 1u);
  return (unsigned short)(u >> 16);
}
__device__ __forceinline__ float bf2f(unsigned short s) {
  return __uint_as_float(((unsigned)s) << 16);
}

// async global -> LDS, 16B per lane. lds ptr must be wave-uniform base;
// HW writes lane i at base + i*16.
__device__ __forceinline__ void glb2lds16(const void* g, void* l) {
  __builtin_amdgcn_global_load_lds(
      (const __attribute__((address_space(1))) unsigned int*)g,
      (__attribute__((address_space(3))) unsigned int*)l, 16, 0, 0);
}

// ---------------------------------------------------------------------------
// f32 -> bf16 cast
// ---------------------------------------------------------------------------
__global__ __launch_bounds__(256) void cast_bf16_kernel(
    const float* __restrict__ in, unsigned short* __restrict__ out, int n) {
  int i = (blockIdx.x * 256 + threadIdx.x) * 4;
  if (i < n) {
    float4 f = *(const float4*)&in[i];
    ushort4 o;
    o.x = f2bf(f.x); o.y = f2bf(f.y); o.z = f2bf(f.z); o.w = f2bf(f.w);
    *(ushort4*)&out[i] = o;
  }
}

// ---------------------------------------------------------------------------
// bf16 MFMA GEMM: C = A(M,K) @ W(N,K)^T (+bias). 128x128 tile, BK=32,
// 4 waves x (64x64). Staging via global_load_lds width=16 (m97 pattern):
// LDS layout [row][kquad] = lane-contiguous chunks, 64B global segments.
// SPLITK>1: blockIdx.z = K-slice; partial output (no bias), summed in LN.
// ---------------------------------------------------------------------------
enum { EP_QKV3_BF16 = 0, EP_RELU_BF16 = 1, EP_F32_PART = 2, EP_BF16_PART = 3 };

template <int EPI, int SPLITK>
__global__ __launch_bounds__(256) void gemm_bt(
    const unsigned short* __restrict__ A, const unsigned short* __restrict__ W,
    const float* __restrict__ bias, void* __restrict__ C0,
    void* __restrict__ C1, void* __restrict__ C2,
    int M, int N, int K) {
  __shared__ unsigned short Alds[128 * 32];
  __shared__ unsigned short Blds[128 * 32];
  const int bm = blockIdx.y * 128, bn = blockIdx.x * 128;
  const int t = threadIdx.x;
  const int lane = t & 63, wid = t >> 6;
  const int wm = (wid >> 1) * 64, wn = (wid & 1) * 64;
  const int r16 = lane & 15, q4 = lane >> 4;
  const int klen = K / SPLITK;
  const int kbeg = (SPLITK > 1) ? blockIdx.z * klen : 0;
  const int kend = kbeg + klen;

  f32x4 acc[4][4] = {};

  for (int k0 = kbeg; k0 < kend; k0 += 32) {
    __syncthreads();
    // chunks c in [0,512): row = c>>2, kquad = c&3; LDS offset = c*16B
    #pragma unroll
    for (int l = 0; l < 2; ++l) {
      int c = t + l * 256;
      int base = ((t & 192) + l * 256) * 8;   // wave-uniform chunk base (u16 units)
      glb2lds16(&A[(size_t)(bm + (c >> 2)) * K + k0 + 8 * (c & 3)], &Alds[base]);
      glb2lds16(&W[(size_t)(bn + (c >> 2)) * K + k0 + 8 * (c & 3)], &Blds[base]);
    }
    __syncthreads();
    bf16x8 af[4], bfv[4];
    #pragma unroll
    for (int i = 0; i < 4; ++i)
      af[i] = *(const bf16x8*)&Alds[((wm + i * 16 + r16) * 4 + q4) * 8];
    #pragma unroll
    for (int j = 0; j < 4; ++j)
      bfv[j] = *(const bf16x8*)&Blds[((wn + j * 16 + r16) * 4 + q4) * 8];
    #pragma unroll
    for (int i = 0; i < 4; ++i)
      #pragma unroll
      for (int j = 0; j < 4; ++j)
        acc[i][j] = __builtin_amdgcn_mfma_f32_16x16x32_bf16(af[i], bfv[j], acc[i][j], 0, 0, 0);
  }

  constexpr bool HASB = (EPI == EP_QKV3_BF16 || EPI == EP_RELU_BF16);
  #pragma unroll
  for (int i = 0; i < 4; ++i) {
    #pragma unroll
    for (int j = 0; j < 4; ++j) {
      #pragma unroll
      for (int r = 0; r < 4; ++r) {
        int m = bm + wm + i * 16 + q4 * 4 + r;
        int n = bn + wn + j * 16 + r16;
        float val = acc[i][j][r] + (HASB ? bias[n] : 0.f);
        if (EPI == EP_QKV3_BF16) {
          int mat = (n >= 1536) ? 2 : (n >= 768 ? 1 : 0);
          int c = n - mat * 768;
          int b = m >> 11, s = m & 2047;
          int h = c >> 6, hd = c & 63;
          unsigned short* dst = (unsigned short*)(mat == 0 ? C0 : (mat == 1 ? C1 : C2));
          dst[(((size_t)b * HH + h) * SS + s) * HDIM + hd] = f2bf(val);
        } else if (EPI == EP_RELU_BF16) {
          ((unsigned short*)C0)[(size_t)m * N + n] = f2bf(fmaxf(val, 0.f));
        } else if (EPI == EP_F32_PART) {
          ((float*)C0)[(size_t)blockIdx.z * M * N + (size_t)m * N + n] = val;
        } else {  // EP_BF16_PART
          ((unsigned short*)C0)[(size_t)blockIdx.z * M * N + (size_t)m * N + n] = f2bf(val);
        }
      }
    }
  }
}

// ---------------------------------------------------------------------------
// Attention v4: MFMA flash attention, causal + analytic ALiBi, 64-row Q
// tiles (grid 32 x 24 = 768 blocks, ~3/CU). Block = 4 waves; wave owns 16
// q-rows. K double-buffered via global_load_lds (issued after 2nd barrier ->
// overlaps compute); V prefetched to VGPRs one tile ahead, transposed into
// LDS (VSTR=66: stride/2 == 1 mod 32 -> 2-way writes, free). exp2-domain
// online softmax. Q,K,V bf16 (B,H,S,HD); out bf16 (B,S,D).
// ---------------------------------------------------------------------------
#define VSTR 66

__global__ __launch_bounds__(256) void attn4_kernel(
    const unsigned short* __restrict__ Q, const unsigned short* __restrict__ K,
    const unsigned short* __restrict__ V, unsigned short* __restrict__ out) {
  __shared__ unsigned short Kl[2][64 * 64];     // [buf][key*8 + kchunk]*8, 8KB each
  __shared__ unsigned short Vt[64 * VSTR];      // [dim][key]
  __shared__ unsigned short Pl[4][16 * VSTR];   // per-wave [q][key]

  const int qt = (SS / 64 - 1) - blockIdx.x;    // reversed: long blocks first
  const int bh = blockIdx.y;
  const int h = bh % HH;
  const int b = bh / HH;
  const int t = threadIdx.x;
  const int lane = t & 63, w = t >> 6;
  const int r16 = lane & 15, q4 = lane >> 4;
  const float k1 = 0.125f * 1.44269504f;                       // scale * log2e
  const float slope2 = exp2f(-8.0f * (float)(h + 1) / 12.0f) * 1.44269504f;
  const int qg0 = qt * 64 + w * 16;

  // Q frags: A[m=r16][k=ks*32+q4*8+j]
  bf16x8 qf[2];
  {
    const unsigned short* qbase = Q + ((size_t)bh * SS + qg0) * HDIM;
    #pragma unroll
    for (int ks = 0; ks < 2; ++ks)
      qf[ks] = *(const bf16x8*)(qbase + r16 * HDIM + ks * 32 + q4 * 8);
  }

  f32x4 O[4] = {};
  float mrow[4], lrow[4];
  #pragma unroll
  for (int r = 0; r < 4; ++r) { mrow[r] = -INFINITY; lrow[r] = 0.f; }

  const unsigned short* Kb = K + (size_t)bh * SS * HDIM;
  const unsigned short* Vb = V + (size_t)bh * SS * HDIM;
  const int kp = t & 31, dq = t >> 5;   // V transpose: key-pair, dim-quad(0..7)
  bf16x8 v0r, v1r;

  // prologue: tile 0 K -> LDS buf0 (async), V -> regs
  #pragma unroll
  for (int l = 0; l < 2; ++l) {
    int c = t + l * 256;
    glb2lds16(&Kb[c * 8], &Kl[0][((t & 192) + l * 256) * 8]);
  }
  v0r = *(const bf16x8*)(Vb + (2 * kp) * HDIM + dq * 8);
  v1r = *(const bf16x8*)(Vb + (2 * kp + 1) * HDIM + dq * 8);

  for (int kt = 0; kt <= qt; ++kt) {
    __syncthreads();   // drains K-lds(kt) + V regs(kt); prior Vt reads done
    #pragma unroll
    for (int e = 0; e < 8; ++e) {
      unsigned u = ((unsigned)(unsigned short)v0r[e]) |
                   (((unsigned)(unsigned short)v1r[e]) << 16);
      *(unsigned*)&Vt[(dq * 8 + e) * VSTR + 2 * kp] = u;
    }
    __syncthreads();   // Vt(kt) visible
    if (kt < qt) {     // prefetch tile kt+1 (overlaps compute below)
      const unsigned short* kg = Kb + (size_t)(kt + 1) * 64 * HDIM;
      #pragma unroll
      for (int l = 0; l < 2; ++l) {
        int c = t + l * 256;
        glb2lds16(&kg[c * 8], &Kl[(kt + 1) & 1][((t & 192) + l * 256) * 8]);
      }
      const unsigned short* vg = Vb + (size_t)(kt + 1) * 64 * HDIM;
      v0r = *(const bf16x8*)(vg + (2 * kp) * HDIM + dq * 8);
      v1r = *(const bf16x8*)(vg + (2 * kp + 1) * HDIM + dq * 8);
    }
    const unsigned short* Kt = Kl[kt & 1];

    // ---- QK^T ----
    f32x4 sc[4] = {};
    #pragma unroll
    for (int ks = 0; ks < 2; ++ks) {
      bf16x8 kf[4];
      #pragma unroll
      for (int jb = 0; jb < 4; ++jb)
        kf[jb] = *(const bf16x8*)&Kt[((jb * 16 + r16) * 8 + ks * 4 + q4) * 8];
      #pragma unroll
      for (int jb = 0; jb < 4; ++jb)
        sc[jb] = __builtin_amdgcn_mfma_f32_16x16x32_bf16(qf[ks], kf[jb], sc[jb], 0, 0, 0);
    }

    // ---- online softmax (exp2 domain). C layout: row=q4*4+r, col=jb*16+r16
    #pragma unroll
    for (int r = 0; r < 4; ++r) {
      int qrow = qg0 + q4 * 4 + r;
      int d0 = kt * 64 + r16 - qrow;
      float tmp[4];
      float mx = -INFINITY;
      #pragma unroll
      for (int jb = 0; jb < 4; ++jb) {
        int diff = d0 + jb * 16;
        float vv = sc[jb][r] * k1 + slope2 * (float)diff;
        vv = (diff <= 0) ? vv : -INFINITY;
        tmp[jb] = vv;
        mx = fmaxf(mx, vv);
      }
      #pragma unroll
      for (int off = 1; off < 16; off <<= 1) mx = fmaxf(mx, __shfl_xor(mx, off, 64));
      float mold = mrow[r];
      float mn = fmaxf(mold, mx);
      float alpha = exp2f(mold - mn);
      mrow[r] = mn;
      float rs = 0.f;
      #pragma unroll
      for (int jb = 0; jb < 4; ++jb) {
        float p = exp2f(tmp[jb] - mn);
        rs += p;
        Pl[w][(q4 * 4 + r) * VSTR + jb * 16 + r16] = f2bf(p);
      }
      #pragma unroll
      for (int off = 1; off < 16; off <<= 1) rs += __shfl_xor(rs, off, 64);
      lrow[r] = lrow[r] * alpha + rs;
      #pragma unroll
      for (int jb = 0; jb < 4; ++jb) O[jb][r] *= alpha;
    }

    // ---- PV: A = P[q][key] (A layout), B = Vt[dim][key] ----
    #pragma unroll
    for (int ks = 0; ks < 2; ++ks) {
      bf16x8 pf = *(const bf16x8*)&Pl[w][r16 * VSTR + ks * 32 + q4 * 8];
      bf16x8 vf[4];
      #pragma unroll
      for (int jb = 0; jb < 4; ++jb)
        vf[jb] = *(const bf16x8*)&Vt[(jb * 16 + r16) * VSTR + ks * 32 + q4 * 8];
      #pragma unroll
      for (int jb = 0; jb < 4; ++jb)
        O[jb] = __builtin_amdgcn_mfma_f32_16x16x32_bf16(pf, vf[jb], O[jb], 0, 0, 0);
    }
  }

  // ---- epilogue ----
  #pragma unroll
  for (int r = 0; r < 4; ++r) {
    float inv = 1.f / lrow[r];
    unsigned short* ob = out + ((size_t)b * SS + qg0 + q4 * 4 + r) * DD + h * HDIM;
    #pragma unroll
    for (int jb = 0; jb < 4; ++jb)
      ob[jb * 16 + r16] = f2bf(O[jb][r] * inv);
  }
}

// ---------------------------------------------------------------------------
// LN1: x1b(bf16) = LN(x + p0 + p1 + bo) * g + be   (O-proj split-K partials)
// LN2: out(f32)  = LN(x1b + f0+f1+f2+f3 + b2) * g + be (FF2 bf16 partials)
// ---------------------------------------------------------------------------
__global__ __launch_bounds__(256) void ln1_kernel(
    const float* __restrict__ x, const float* __restrict__ p,
    const float* __restrict__ bo, const float* __restrict__ g,
    const float* __restrict__ be, unsigned short* __restrict__ outb) {
  const int row = blockIdx.x, t = threadIdx.x;
  const size_t base = (size_t)row * DD;
  const size_t str = (size_t)BB * SS * DD;
  float v[3];
  float s = 0.f;
  #pragma unroll
  for (int i = 0; i < 3; ++i) {
    int c = t + i * 256;
    v[i] = x[base + c] + p[base + c] + p[str + base + c] + bo[c];
    s += v[i];
  }
  __shared__ float red[256];
  red[t] = s; __syncthreads();
  for (int off = 128; off > 0; off >>= 1) { if (t < off) red[t] += red[t + off]; __syncthreads(); }
  float mu = red[0] * (1.0f / DD);
  __syncthreads();
  float s2 = 0.f;
  #pragma unroll
  for (int i = 0; i < 3; ++i) { float d = v[i] - mu; s2 += d * d; }
  red[t] = s2; __syncthreads();
  for (int off = 128; off > 0; off >>= 1) { if (t < off) red[t] += red[t + off]; __syncthreads(); }
  float rstd = rsqrtf(red[0] * (1.0f / DD) + 1e-5f);
  #pragma unroll
  for (int i = 0; i < 3; ++i) {
    int c = t + i * 256;
    outb[base + c] = f2bf((v[i] - mu) * rstd * g[c] + be[c]);
  }
}

__global__ __launch_bounds__(256) void ln2_kernel(
    const unsigned short* __restrict__ a, const unsigned short* __restrict__ f,
    const float* __restrict__ b2, const float* __restrict__ g,
    const float* __restrict__ be, float* __restrict__ out) {
  const int row = blockIdx.x, t = threadIdx.x;
  const size_t base = (size_t)row * DD;
  const size_t str = (size_t)BB * SS * DD;
  float v[3];
  float s = 0.f;
  #pragma unroll
  for (int i = 0; i < 3; ++i) {
    int c = t + i * 256;
    size_t ix = base + c;
    v[i] = bf2f(a[ix]) + bf2f(f[ix]) + bf2f(f[str + ix]) +
           bf2f(f[2 * str + ix]) + bf2f(f[3 * str + ix]) + b2[c];
    s += v[i];
  }
  __shared__ float red[256];
  red[t] = s; __syncthreads();
  for (int off = 128; off > 0; off >>= 1) { if (t < off) red[t] += red[t + off]; __syncthreads(); }
  float mu = red[0] * (1.0f / DD);
  __syncthreads();
  float s2 = 0.f;
  #pragma unroll
  for (int i = 0; i < 3; ++i) { float d = v[i] - mu; s2 += d * d; }
  red[t] = s2; __syncthreads();
  for (int off = 128; off > 0; off >>= 1) { if (t < off) red[t] += red[t + off]; __syncthreads(); }
  float rstd = rsqrtf(red[0] * (1.0f / DD) + 1e-5f);
  #pragma unroll
  for (int i = 0; i < 3; ++i) {
    int c = t + i * 256;
    out[base + c] = (v[i] - mu) * rstd * g[c] + be[c];
  }
}

// ---------------------------------------------------------------------------
extern "C" void kernel_launch(void* const* d_in, const int* in_sizes, int n_in,
                              void* d_out, int out_size, void* d_ws, size_t ws_size,
                              hipStream_t stream) {
  const float* x   = (const float*)d_in[0];
  // d_in[1]=mask, d_in[2]=alibi — analytic in-kernel.
  const float* wq  = (const float*)d_in[3];
  const float* bq  = (const float*)d_in[4];
  const float* wk  = (const float*)d_in[5];
  const float* bk  = (const float*)d_in[6];
  const float* wv  = (const float*)d_in[7];
  const float* bv  = (const float*)d_in[8];
  const float* wo  = (const float*)d_in[9];
  const float* bo  = (const float*)d_in[10];
  const float* w1  = (const float*)d_in[11];
  const float* b1  = (const float*)d_in[12];
  const float* w2  = (const float*)d_in[13];
  const float* b2  = (const float*)d_in[14];
  const float* g1  = (const float*)d_in[15];
  const float* be1 = (const float*)d_in[16];
  const float* g2  = (const float*)d_in[17];
  const float* be2 = (const float*)d_in[18];
  float* out = (float*)d_out;

  char* ws = (char*)d_ws;
  // --- workspace layout (70,788,096 B total; liveness-checked reuse) ---
  unsigned short* wqkvb = (unsigned short*)(ws + 0);          //  3,538,944
  unsigned short* wob   = (unsigned short*)(ws + 3538944);    //  1,179,648
  unsigned short* w1b   = (unsigned short*)(ws + 4718592);    //  4,718,592
  unsigned short* w2b   = (unsigned short*)(ws + 9437184);    //  4,718,592 (live->FF2)
  unsigned short* xb    = (unsigned short*)(ws + 14155776);   //  6,291,456
  float*          bqkv  = (float*)(ws + 20447232);            //      9,216
  unsigned short* qb    = (unsigned short*)(ws + 20456448);   //  6,291,456
  unsigned short* kb    = (unsigned short*)(ws + 26747904);   //  6,291,456
  unsigned short* vb    = (unsigned short*)(ws + 33039360);   //  6,291,456
  unsigned short* at    = (unsigned short*)(ws + 39330816);   //  6,291,456
  unsigned short* f1    = (unsigned short*)(ws + 45622272);   // 25,165,824 -> 70,788,096
  // reuse:
  float*          pj    = (float*)(ws + 14155776);            // 2x12.58M over xb..vb (dead post-attn)
  unsigned short* x1b   = (unsigned short*)(ws + 39330816);   // over at (dead post-Oproj)
  unsigned short* f2b   = (unsigned short*)(ws + 14155776);   // 4x6.29M over pj (dead post-ln1)

  const int M = BB * SS;  // 4096
  dim3 blk(256);

  // bf16 casts; wq/wk/wv concatenated row-wise into one (2304,768) matrix
  cast_bf16_kernel<<<dim3(M * DD / 1024), blk, 0, stream>>>(x, xb, M * DD);
  cast_bf16_kernel<<<dim3(DD * DD / 1024), blk, 0, stream>>>(wq, wqkvb, DD * DD);
  cast_bf16_kernel<<<dim3(DD * DD / 1024), blk, 0, stream>>>(wk, wqkvb + DD * DD, DD * DD);
  cast_bf16_kernel<<<dim3(DD * DD / 1024), blk, 0, stream>>>(wv, wqkvb + 2 * DD * DD, DD * DD);
  cast_bf16_kernel<<<dim3(DD * DD / 1024), blk, 0, stream>>>(wo, wob, DD * DD);
  cast_bf16_kernel<<<dim3(FFD * DD / 1024), blk, 0, stream>>>(w1, w1b, FFD * DD);
  cast_bf16_kernel<<<dim3(FFD * DD / 1024), blk, 0, stream>>>(w2, w2b, FFD * DD);
  hipMemcpyAsync(bqkv, bq, DD * sizeof(float), hipMemcpyDeviceToDevice, stream);
  hipMemcpyAsync(bqkv + DD, bk, DD * sizeof(float), hipMemcpyDeviceToDevice, stream);
  hipMemcpyAsync(bqkv + 2 * DD, bv, DD * sizeof(float), hipMemcpyDeviceToDevice, stream);

  // fused QKV projection -> bf16 (B,H,S,HD) x3
  gemm_bt<EP_QKV3_BF16, 1><<<dim3(3 * DD / 128, M / 128, 1), blk, 0, stream>>>(
      xb, wqkvb, bqkv, qb, kb, vb, M, 3 * DD, DD);

  // MFMA flash attention -> at (bf16, (B,S,D))
  attn4_kernel<<<dim3(SS / 64, BB * HH), blk, 0, stream>>>(qb, kb, vb, at);

  // output projection, split-K=2 -> f32 partials (bias folded into ln1)
  gemm_bt<EP_F32_PART, 2><<<dim3(DD / 128, M / 128, 2), blk, 0, stream>>>(
      at, wob, nullptr, pj, nullptr, nullptr, M, DD, DD);

  // x1b = bf16(LN(x + pj0 + pj1 + bo))
  ln1_kernel<<<dim3(M), blk, 0, stream>>>(x, pj, bo, g1, be1, x1b);

  // FF1: relu(x1 @ w1^T + b1) -> f1 (bf16)
  gemm_bt<EP_RELU_BF16, 1><<<dim3(FFD / 128, M / 128, 1), blk, 0, stream>>>(
      x1b, w1b, b1, f1, nullptr, nullptr, M, FFD, DD);

  // FF2, split-K=4 -> bf16 partials (bias folded into ln2)
  gemm_bt<EP_BF16_PART, 4><<<dim3(DD / 128, M / 128, 4), blk, 0, stream>>>(
      f1, w2b, nullptr, f2b, nullptr, nullptr, M, DD, FFD);

  // out = LN(x1 + sum(f2 partials) + b2)
  ln2_kernel<<<dim3(M), blk, 0, stream>>>(x1b, f2b, b2, g2, be2, out);
}